// Round 4
// baseline (4972.463 us; speedup 1.0000x reference)
//
#include <hip/hip_runtime.h>
#include <stdint.h>

// ---------------------------------------------------------------------------
// BasicLSTM on MI355X — persistent pipelined 2-layer LSTM, round 4.
//
// Structure: 256 WGs x 256 threads, 1 block/CU (launch_bounds 256,1).
// 8 batch groups x 16 rows; per group 32 WGs (2 layers x 16 col-slices).
// Weights live in registers (MFMA B-frags) for all 513 epochs.
//
// ROUND-4 CHANGES (sync was 85% of step time per rocprof):
//  * Central counter barrier -> per-producer TAG words (release/acquire),
//    128-B spaced. Consumers poll all 32 group tags lane-parallel.
//    Removes the fetch_add leg + counter contention.
//  * Packed B-tile layout [i|f],[g|o] per 8 hidden cols -> gate pairs sit in
//    lanes l / l^8 of the SAME wave: nonlinearity via shfl_xor, no LDS
//    gate round trip (saves 2 syncthreads + LDS traffic).
//  * h written directly as 2-B agent-scope stores (no hexch packing).
//  * x loads issued into registers BEFORE the tag wait (latency overlap).
//  * A-tile pitch 1600/2112 (== 64 mod 128) to cut ds_read_b128 conflicts.
// ---------------------------------------------------------------------------

using s16x8 = __attribute__((ext_vector_type(8))) short;   // 8 bf16 = 4 VGPRs
using f32x4 = __attribute__((ext_vector_type(4))) float;
typedef unsigned long long ull;

#define WSB0_OFF 0           // ushort elems; L0 frags: 16*8*24*512 = 1572864
#define WSB1_OFF 1572864     // L1 frags: 16*8*32*512 = 2097152
#define HB0_OFF  3670016     // h0 slots: 2*128*512 = 131072
#define HB1_OFF  3801088     // h1 slots: 131072 (end 3932160)
#define TAGS_BYTE_OFF 7864320  // 256 tags * 128 B = 32 KB

__device__ __forceinline__ float bf2f(unsigned short u) {
    unsigned v = ((unsigned)u) << 16;
    return __builtin_bit_cast(float, v);
}
__device__ __forceinline__ unsigned short f2bf(float f) {
    unsigned x = __builtin_bit_cast(unsigned, f);
    x += 0x7FFFu + ((x >> 16) & 1u);          // RNE (finite values only)
    return (unsigned short)(x >> 16);
}
__device__ __forceinline__ float sigm(float x) { return 1.f / (1.f + __expf(-x)); }
__device__ __forceinline__ float tanhc(float x) {
    x = fminf(15.f, fmaxf(-15.f, x));
    float e = __expf(-2.f * x);
    return (1.f - e) / (1.f + e);
}

// ---------------------------------------------------------------------------
// Prep: weights fp32 -> bf16 MFMA B-frags in packed-gate layout; zero the
// h slots that epoch-0/1 consumers read as "h(-1)"; zero tags.
// Packed layout: slice rt, wave w owns hidden cols j = w*8..w*8+7;
//   tile (w,0) cols = [i(j0..7) | f(j0..7)], tile (w,1) = [g(j0..7) | o(j0..7)].
// ---------------------------------------------------------------------------
__device__ __forceinline__ void store_frag(unsigned short* dst, int n, int kc, int KT,
                                           const float* src) {
    s16x8 v;
#pragma unroll
    for (int e = 0; e < 8; ++e) v[e] = (short)f2bf(src[e]);
    int gate = n >> 9, hid = n & 511;
    int rt = hid >> 5;
    int w  = (hid >> 3) & 3;
    int t  = gate >> 1;
    int lo = (gate & 1) * 8 + (hid & 7);
    int tileIdx = w * 2 + t;
    int kt = kc >> 2, q = kc & 3;
    int lane = q * 16 + lo;
    size_t off = ((((size_t)rt * 8 + tileIdx) * KT + kt) * 64 + lane) * 8;
    *(s16x8*)(dst + off) = v;
}

__global__ void k_prep(const float* __restrict__ wih0, const float* __restrict__ whh0,
                       const float* __restrict__ wih1, const float* __restrict__ whh1,
                       unsigned short* __restrict__ wsB0, unsigned short* __restrict__ wsB1,
                       unsigned short* __restrict__ hb0, unsigned short* __restrict__ hb1,
                       unsigned* __restrict__ tags) {
    int idx = blockIdx.x * 256 + threadIdx.x;
    if (idx < 196608) {                       // L0: 2048 rows x 96 k-chunks
        int n = idx / 96, kc = idx - n * 96;
        int k = kc * 8;
        const float* src = (k < 256) ? (wih0 + (size_t)n * 256 + k)
                                     : (whh0 + (size_t)n * 512 + (k - 256));
        store_frag(wsB0, n, kc, 24, src);
    } else if (idx < 458752) {                // L1: 2048 rows x 128 k-chunks
        int j = idx - 196608;
        int n = j >> 7, kc = j & 127;
        int k = kc * 8;
        const float* src = (k < 512) ? (wih1 + (size_t)n * 512 + k)
                                     : (whh1 + (size_t)n * 512 + (k - 512));
        store_frag(wsB1, n, kc, 32, src);
    } else {
        int z = idx - 458752;
        if (z < 8192) {                       // zero hb0 slot 1 (h0(-1))
            ull* p = (ull*)(hb0 + 65536 + (size_t)z * 8);
            p[0] = 0ull; p[1] = 0ull;
        } else if (z < 16384) {               // zero hb1 slot 0 (h1(-1))
            ull* p = (ull*)(hb1 + (size_t)(z - 8192) * 8);
            p[0] = 0ull; p[1] = 0ull;
        } else if (z < 16640) {               // zero 256 tag words (128-B spaced)
            tags[(size_t)(z - 16384) * 32] = 0u;
        }
    }
}

// ---------------------------------------------------------------------------
// Persistent LSTM kernel
// ---------------------------------------------------------------------------
template <int LAYER, int KT>
__device__ __forceinline__ void run_layer(const float* __restrict__ x,
                                          const unsigned short* __restrict__ wsB,
                                          unsigned short* hsrc0,   // L0: hb0 ; L1: hb0 (y0)
                                          unsigned short* hself,   // write target (hb0/hb1)
                                          unsigned* tags,          // group tag base (32 tags)
                                          unsigned* mytag,
                                          float bv0, float bv1,
                                          int g, int rt, int w, int lane, int tid,
                                          char* At) {
    constexpr int PITCH = (LAYER == 0) ? 1600 : 2112;   // bytes/row, ==64 mod 128
    const int lm = lane & 15, lq = lane >> 4;

    // --- weight fragments into registers/AGPRs (live across all epochs) ---
    s16x8 bfr0[KT], bfr1[KT];
    {
        const unsigned short* base = wsB + (((size_t)rt * 8 + 2 * w) * KT) * 512;
#pragma unroll
        for (int kt = 0; kt < KT; ++kt) {
            bfr0[kt] = *(const s16x8*)(base + ((size_t)kt * 64 + lane) * 8);
            bfr1[kt] = *(const s16x8*)(base + (((size_t)KT + kt) * 64 + lane) * 8);
        }
    }

    float cst[4] = {0.f, 0.f, 0.f, 0.f};      // cell state: (b=lq*4+r, j=w*8+(lm&7))

#pragma unroll 1
    for (int s = 0; s <= 512; ++s) {
        const bool active = LAYER ? (s >= 1) : (s < 512);
        const int pr = (s + 1) & 1;           // read slot
        const int pw = s & 1;                 // write slot

        // ---- L0: issue x loads into registers BEFORE the tag wait ----
        f32x4 xa[2], xb[2];
        int xrow[2], xch[2];
        if (LAYER == 0 && active) {
#pragma unroll
            for (int i = 0; i < 2; ++i) {
                int task = tid + i * 256;     // 16 rows x 32 chunks (8 fp32 each)
                xrow[i] = task >> 5; xch[i] = task & 31;
                const float* src = x + ((size_t)(g * 16 + xrow[i]) * 512 + s) * 256 + xch[i] * 8;
                xa[i] = *(const f32x4*)(src);
                xb[i] = *(const f32x4*)(src + 4);
            }
        }

        // ---- gate: all 32 group tags >= s (lane-parallel acquire polls) ----
        if (tid < 32) {
            unsigned* tp = tags + (size_t)tid * 32;
            while (__hip_atomic_load(tp, __ATOMIC_ACQUIRE, __HIP_MEMORY_SCOPE_AGENT) < (unsigned)s)
                __builtin_amdgcn_s_sleep(1);
        }
        __syncthreads();

        if (active) {
            // ---- stage A tile into LDS ----
            if (LAYER == 0) {
#pragma unroll
                for (int i = 0; i < 2; ++i) {  // x part: cvt + store
                    s16x8 v;
#pragma unroll
                    for (int e = 0; e < 4; ++e) { v[e] = (short)f2bf(xa[i][e]); v[4 + e] = (short)f2bf(xb[i][e]); }
                    *(s16x8*)(At + xrow[i] * PITCH + xch[i] * 16) = v;
                }
#pragma unroll
                for (int i = 0; i < 4; ++i) {  // h part: 16 rows x 64 chunks (16 B)
                    int task = tid + i * 256;
                    int row = task >> 6, c8 = task & 63;
                    const ull* sp = (const ull*)(hsrc0 + (size_t)(pr * 128 + g * 16 + row) * 512 + c8 * 8);
                    ull v0 = __hip_atomic_load(sp,     __ATOMIC_RELAXED, __HIP_MEMORY_SCOPE_AGENT);
                    ull v1 = __hip_atomic_load(sp + 1, __ATOMIC_RELAXED, __HIP_MEMORY_SCOPE_AGENT);
                    ull* d = (ull*)(At + row * PITCH + 512 + c8 * 16);
                    d[0] = v0; d[1] = v1;
                }
            } else {
#pragma unroll
                for (int i = 0; i < 8; ++i) {  // 16 rows x 128 chunks (16 B)
                    int task = tid + i * 256;
                    int row = task >> 7, c8 = task & 127;
                    const unsigned short* sp = (c8 < 64)
                        ? (hsrc0 + (size_t)(pr * 128 + g * 16 + row) * 512 + c8 * 8)
                        : (hself + (size_t)(pr * 128 + g * 16 + row) * 512 + (c8 - 64) * 8);
                    ull v0 = __hip_atomic_load((const ull*)sp,     __ATOMIC_RELAXED, __HIP_MEMORY_SCOPE_AGENT);
                    ull v1 = __hip_atomic_load((const ull*)sp + 1, __ATOMIC_RELAXED, __HIP_MEMORY_SCOPE_AGENT);
                    ull* d = (ull*)(At + row * PITCH + c8 * 16);
                    d[0] = v0; d[1] = v1;
                }
            }
            __syncthreads();

            // ---- MFMA K-loop: acc0 = [i|f], acc1 = [g|o] for 8 hidden cols ----
            f32x4 acc0 = {0.f, 0.f, 0.f, 0.f}, acc1 = {0.f, 0.f, 0.f, 0.f};
            const char* ap = At + lm * PITCH + lq * 16;
#pragma unroll
            for (int kt = 0; kt < KT; ++kt) {
                s16x8 a = *(const s16x8*)(ap + kt * 64);
                acc0 = __builtin_amdgcn_mfma_f32_16x16x32_bf16(a, bfr0[kt], acc0, 0, 0, 0);
                acc1 = __builtin_amdgcn_mfma_f32_16x16x32_bf16(a, bfr1[kt], acc1, 0, 0, 0);
            }

            // ---- nonlinearity via shfl_xor(8,16); no LDS round trip ----
            const int jcol = rt * 32 + w * 8 + (lm & 7);
            const bool hi = (lm & 8) != 0;
#pragma unroll
            for (int r = 0; r < 4; ++r) {
                float a0 = acc0[r] + bv0;
                float a1 = acc1[r] + bv1;
                float a0x = __shfl_xor(a0, 8, 16);
                float a1x = __shfl_xor(a1, 8, 16);
                float iv = hi ? a0x : a0;
                float fv = hi ? a0  : a0x;
                float gv = hi ? a1x : a1;
                float ov = hi ? a1  : a1x;
                float cn = sigm(fv) * cst[r] + sigm(iv) * tanhc(gv);
                cst[r] = cn;
                float h = sigm(ov) * tanhc(cn);
                if (!hi) {                     // lanes lm<8 store (dup halves agree)
                    int b = lq * 4 + r;
                    __hip_atomic_store(
                        hself + (size_t)(pw * 128 + g * 16 + b) * 512 + jcol,
                        f2bf(h), __ATOMIC_RELAXED, __HIP_MEMORY_SCOPE_AGENT);
                }
            }
        }

        // ---- publish: drain stores (pre-barrier waitcnt), release tag ----
        __syncthreads();
        if (tid == 0)
            __hip_atomic_store(mytag, (unsigned)(s + 1), __ATOMIC_RELEASE, __HIP_MEMORY_SCOPE_AGENT);
    }
}

__launch_bounds__(256, 1)
__global__ void k_lstm(const float* __restrict__ x,
                       const float* __restrict__ b0,
                       const float* __restrict__ b1,
                       const unsigned short* __restrict__ wsB0,
                       const unsigned short* __restrict__ wsB1,
                       unsigned short* hb0, unsigned short* hb1,
                       unsigned* tags) {
    __shared__ __align__(16) char Atile[16 * 2112];      // A tile, max pitch (L1)

    const int tid = threadIdx.x;
    const int g = blockIdx.x & 7, sub = blockIdx.x >> 3;
    const int layer = sub >> 4, rt = sub & 15;
    const int w = tid >> 6, lane = tid & 63;
    const int lm = lane & 15;

    unsigned* gtags = tags + (size_t)g * 32 * 32;        // 32 tags, 128-B spaced
    unsigned* mytag = gtags + (size_t)(layer * 16 + rt) * 32;

    const float* bias = layer ? b1 : b0;
    const int jsub = rt * 32 + w * 8 + (lm & 7);
    const int G0 = (lm & 8) ? 1 : 0;                     // acc0: i | f
    const float bv0 = bias[G0 * 512 + jsub];
    const float bv1 = bias[(G0 + 2) * 512 + jsub];       // acc1: g | o

    if (layer == 0)
        run_layer<0, 24>(x, wsB0, hb0, hb0, gtags, mytag, bv0, bv1,
                         g, rt, w, lane, tid, Atile);
    else
        run_layer<1, 32>(x, wsB1, hb0, hb1, gtags, mytag, bv0, bv1,
                         g, rt, w, lane, tid, Atile);
}

// ---------------------------------------------------------------------------
// FC epilogue: out[i] = dot(hn[i], fc_w) + fc_b, hn = [h0(511); h1(511)]
// h0(511) was written at epoch 511 -> slot 1; h1(511) at epoch 512 -> slot 0.
// ---------------------------------------------------------------------------
__global__ void k_fc(const unsigned short* __restrict__ hb0,
                     const unsigned short* __restrict__ hb1,
                     const float* __restrict__ fcw, const float* __restrict__ fcb,
                     float* __restrict__ out) {
    int i = blockIdx.x, lane = threadIdx.x;
    const unsigned short* hrow = (i < 128) ? (hb0 + (size_t)(128 + i) * 512)      // slot 1
                                           : (hb1 + (size_t)(i - 128) * 512);     // slot 0
    float ssum = 0.f;
    int j0 = lane * 8;
#pragma unroll
    for (int e = 0; e < 8; ++e) ssum += bf2f(hrow[j0 + e]) * fcw[j0 + e];
#pragma unroll
    for (int off2 = 32; off2 > 0; off2 >>= 1) ssum += __shfl_down(ssum, off2);
    if (lane == 0) out[i] = ssum + fcb[0];
}

// ---------------------------------------------------------------------------
extern "C" void kernel_launch(void* const* d_in, const int* in_sizes, int n_in,
                              void* d_out, int out_size, void* d_ws, size_t ws_size,
                              hipStream_t stream) {
    const float* x    = (const float*)d_in[0];
    const float* wih0 = (const float*)d_in[1];
    const float* whh0 = (const float*)d_in[2];
    const float* b0   = (const float*)d_in[3];
    const float* wih1 = (const float*)d_in[4];
    const float* whh1 = (const float*)d_in[5];
    const float* b1   = (const float*)d_in[6];
    const float* fcw  = (const float*)d_in[7];
    const float* fcb  = (const float*)d_in[8];

    unsigned short* wsB0 = (unsigned short*)d_ws;
    unsigned short* wsB1 = wsB0 + WSB1_OFF;
    unsigned short* hb0  = wsB0 + HB0_OFF;
    unsigned short* hb1  = wsB0 + HB1_OFF;
    unsigned* tags = (unsigned*)((char*)d_ws + TAGS_BYTE_OFF);
    float* out = (float*)d_out;

    k_prep<<<dim3(1857), dim3(256), 0, stream>>>(wih0, whh0, wih1, whh1,
                                                 wsB0, wsB1, hb0, hb1, tags);

    k_lstm<<<dim3(256), dim3(256), 0, stream>>>(x, b0, b1, wsB0, wsB1, hb0, hb1, tags);

    k_fc<<<dim3(256), dim3(64), 0, stream>>>(hb0, hb1, fcw, fcb, out);
}

// Round 5
// 2862.461 us; speedup vs baseline: 1.7371x; 1.7371x over previous
//
#include <hip/hip_runtime.h>
#include <stdint.h>

// ---------------------------------------------------------------------------
// BasicLSTM on MI355X — persistent pipelined 2-layer LSTM, round 5.
//
// Structure: 256 WGs x 256 threads, 1 block/CU (launch_bounds 256,1).
// 8 batch groups x 16 rows; per group 32 WGs (2 layers x 16 col-slices).
// Weights live in registers (MFMA B-frags) for all 513 epochs.
//
// ROUND-5 CHANGES (acquire/release cache-maintenance was the invariant cost):
//  * ALL hot-loop comm ops -> __ATOMIC_RELAXED + __HIP_MEMORY_SCOPE_SYSTEM.
//    Relaxed system atomics emit plain sc0+sc1 accesses (L1/L2 bypass, served
//    at the device coherence point) with NO buffer_inv / buffer_wbl2.
//    Rounds 3+4 used acquire/release at agent scope -> whole-L2
//    writeback/invalidate per poll iteration x 256 WGs = the ~8 us/step
//    floor both protocols shared.
//    Ordering is structural: __syncthreads() drains vmcnt(0) per wave
//    (h stores complete at L3 before the tag publish that follows the
//    barrier); consumer h loads sit after the post-poll barrier.
//  * h stores: in-register 8x4 shfl transpose -> packed 8-B stores
//    (round 4's scattered 2-B stores doubled WRITE_SIZE via partial-sector
//    write-through; this also shrinks the pre-barrier store drain).
// ---------------------------------------------------------------------------

using s16x8 = __attribute__((ext_vector_type(8))) short;   // 8 bf16 = 4 VGPRs
using f32x4 = __attribute__((ext_vector_type(4))) float;
typedef unsigned long long ull;

#define WSB0_OFF 0           // ushort elems; L0 frags: 16*8*24*512 = 1572864
#define WSB1_OFF 1572864     // L1 frags: 16*8*32*512 = 2097152
#define HB0_OFF  3670016     // h0 slots: 2*128*512 = 131072
#define HB1_OFF  3801088     // h1 slots: 131072 (end 3932160)
#define TAGS_BYTE_OFF 7864320  // 256 tags * 128 B = 32 KB

__device__ __forceinline__ float bf2f(unsigned short u) {
    unsigned v = ((unsigned)u) << 16;
    return __builtin_bit_cast(float, v);
}
__device__ __forceinline__ unsigned short f2bf(float f) {
    unsigned x = __builtin_bit_cast(unsigned, f);
    x += 0x7FFFu + ((x >> 16) & 1u);          // RNE (finite values only)
    return (unsigned short)(x >> 16);
}
__device__ __forceinline__ float sigm(float x) { return 1.f / (1.f + __expf(-x)); }
__device__ __forceinline__ float tanhc(float x) {
    x = fminf(15.f, fmaxf(-15.f, x));
    float e = __expf(-2.f * x);
    return (1.f - e) / (1.f + e);
}

// ---------------------------------------------------------------------------
// Prep: weights fp32 -> bf16 MFMA B-frags in packed-gate layout; zero the
// h slots that epoch-0/1 consumers read as "h(-1)"; zero tags.
// Packed layout: slice rt, wave w owns hidden cols j = w*8..w*8+7;
//   tile (w,0) cols = [i(j0..7) | f(j0..7)], tile (w,1) = [g(j0..7) | o(j0..7)].
// ---------------------------------------------------------------------------
__device__ __forceinline__ void store_frag(unsigned short* dst, int n, int kc, int KT,
                                           const float* src) {
    s16x8 v;
#pragma unroll
    for (int e = 0; e < 8; ++e) v[e] = (short)f2bf(src[e]);
    int gate = n >> 9, hid = n & 511;
    int rt = hid >> 5;
    int w  = (hid >> 3) & 3;
    int t  = gate >> 1;
    int lo = (gate & 1) * 8 + (hid & 7);
    int tileIdx = w * 2 + t;
    int kt = kc >> 2, q = kc & 3;
    int lane = q * 16 + lo;
    size_t off = ((((size_t)rt * 8 + tileIdx) * KT + kt) * 64 + lane) * 8;
    *(s16x8*)(dst + off) = v;
}

__global__ void k_prep(const float* __restrict__ wih0, const float* __restrict__ whh0,
                       const float* __restrict__ wih1, const float* __restrict__ whh1,
                       unsigned short* __restrict__ wsB0, unsigned short* __restrict__ wsB1,
                       unsigned short* __restrict__ hb0, unsigned short* __restrict__ hb1,
                       unsigned* __restrict__ tags) {
    int idx = blockIdx.x * 256 + threadIdx.x;
    if (idx < 196608) {                       // L0: 2048 rows x 96 k-chunks
        int n = idx / 96, kc = idx - n * 96;
        int k = kc * 8;
        const float* src = (k < 256) ? (wih0 + (size_t)n * 256 + k)
                                     : (whh0 + (size_t)n * 512 + (k - 256));
        store_frag(wsB0, n, kc, 24, src);
    } else if (idx < 458752) {                // L1: 2048 rows x 128 k-chunks
        int j = idx - 196608;
        int n = j >> 7, kc = j & 127;
        int k = kc * 8;
        const float* src = (k < 512) ? (wih1 + (size_t)n * 512 + k)
                                     : (whh1 + (size_t)n * 512 + (k - 512));
        store_frag(wsB1, n, kc, 32, src);
    } else {
        int z = idx - 458752;
        if (z < 8192) {                       // zero hb0 slot 1 (h0(-1))
            ull* p = (ull*)(hb0 + 65536 + (size_t)z * 8);
            p[0] = 0ull; p[1] = 0ull;
        } else if (z < 16384) {               // zero hb1 slot 0 (h1(-1))
            ull* p = (ull*)(hb1 + (size_t)(z - 8192) * 8);
            p[0] = 0ull; p[1] = 0ull;
        } else if (z < 16640) {               // zero 256 tag words (128-B spaced)
            tags[(size_t)(z - 16384) * 32] = 0u;
        }
    }
}

// ---------------------------------------------------------------------------
// Persistent LSTM kernel
// ---------------------------------------------------------------------------
template <int LAYER, int KT>
__device__ __forceinline__ void run_layer(const float* __restrict__ x,
                                          const unsigned short* __restrict__ wsB,
                                          unsigned short* hsrc0,   // L0: hb0 ; L1: hb0 (y0)
                                          unsigned short* hself,   // write target (hb0/hb1)
                                          unsigned* tags,          // group tag base (32 tags)
                                          unsigned* mytag,
                                          float bv0, float bv1,
                                          int g, int rt, int w, int lane, int tid,
                                          char* At) {
    constexpr int PITCH = (LAYER == 0) ? 1600 : 2112;   // bytes/row, ==64 mod 128
    const int lm = lane & 15, lq = lane >> 4;

    // --- weight fragments into registers/AGPRs (live across all epochs) ---
    s16x8 bfr0[KT], bfr1[KT];
    {
        const unsigned short* base = wsB + (((size_t)rt * 8 + 2 * w) * KT) * 512;
#pragma unroll
        for (int kt = 0; kt < KT; ++kt) {
            bfr0[kt] = *(const s16x8*)(base + ((size_t)kt * 64 + lane) * 8);
            bfr1[kt] = *(const s16x8*)(base + (((size_t)KT + kt) * 64 + lane) * 8);
        }
    }

    float cst[4] = {0.f, 0.f, 0.f, 0.f};      // cell state: (b=lq*4+r, j=w*8+(lm&7))

#pragma unroll 1
    for (int s = 0; s <= 512; ++s) {
        const bool active = LAYER ? (s >= 1) : (s < 512);
        const int pr = (s + 1) & 1;           // read slot
        const int pw = s & 1;                 // write slot

        // ---- L0: issue x loads into registers BEFORE the tag wait ----
        f32x4 xa[2], xb[2];
        int xrow[2], xch[2];
        if (LAYER == 0 && active) {
#pragma unroll
            for (int i = 0; i < 2; ++i) {
                int task = tid + i * 256;     // 16 rows x 32 chunks (8 fp32 each)
                xrow[i] = task >> 5; xch[i] = task & 31;
                const float* src = x + ((size_t)(g * 16 + xrow[i]) * 512 + s) * 256 + xch[i] * 8;
                xa[i] = *(const f32x4*)(src);
                xb[i] = *(const f32x4*)(src + 4);
            }
        }

        // ---- gate: all 32 group tags >= s (lane-parallel RELAXED polls) ----
        if (tid < 32) {
            unsigned* tp = tags + (size_t)tid * 32;
            while (__hip_atomic_load(tp, __ATOMIC_RELAXED, __HIP_MEMORY_SCOPE_SYSTEM) < (unsigned)s)
                __builtin_amdgcn_s_sleep(1);
        }
        __syncthreads();

        if (active) {
            // ---- stage A tile into LDS ----
            if (LAYER == 0) {
#pragma unroll
                for (int i = 0; i < 2; ++i) {  // x part: cvt + store
                    s16x8 v;
#pragma unroll
                    for (int e = 0; e < 4; ++e) { v[e] = (short)f2bf(xa[i][e]); v[4 + e] = (short)f2bf(xb[i][e]); }
                    *(s16x8*)(At + xrow[i] * PITCH + xch[i] * 16) = v;
                }
#pragma unroll
                for (int i = 0; i < 4; ++i) {  // h part: 16 rows x 64 chunks (16 B)
                    int task = tid + i * 256;
                    int row = task >> 6, c8 = task & 63;
                    const ull* sp = (const ull*)(hsrc0 + (size_t)(pr * 128 + g * 16 + row) * 512 + c8 * 8);
                    ull v0 = __hip_atomic_load(sp,     __ATOMIC_RELAXED, __HIP_MEMORY_SCOPE_SYSTEM);
                    ull v1 = __hip_atomic_load(sp + 1, __ATOMIC_RELAXED, __HIP_MEMORY_SCOPE_SYSTEM);
                    ull* d = (ull*)(At + row * PITCH + 512 + c8 * 16);
                    d[0] = v0; d[1] = v1;
                }
            } else {
#pragma unroll
                for (int i = 0; i < 8; ++i) {  // 16 rows x 128 chunks (16 B)
                    int task = tid + i * 256;
                    int row = task >> 7, c8 = task & 127;
                    const unsigned short* sp = (c8 < 64)
                        ? (hsrc0 + (size_t)(pr * 128 + g * 16 + row) * 512 + c8 * 8)
                        : (hself + (size_t)(pr * 128 + g * 16 + row) * 512 + (c8 - 64) * 8);
                    ull v0 = __hip_atomic_load((const ull*)sp,     __ATOMIC_RELAXED, __HIP_MEMORY_SCOPE_SYSTEM);
                    ull v1 = __hip_atomic_load((const ull*)sp + 1, __ATOMIC_RELAXED, __HIP_MEMORY_SCOPE_SYSTEM);
                    ull* d = (ull*)(At + row * PITCH + c8 * 16);
                    d[0] = v0; d[1] = v1;
                }
            }
            __syncthreads();

            // ---- MFMA K-loop: acc0 = [i|f], acc1 = [g|o] for 8 hidden cols ----
            f32x4 acc0 = {0.f, 0.f, 0.f, 0.f}, acc1 = {0.f, 0.f, 0.f, 0.f};
            const char* ap = At + lm * PITCH + lq * 16;
#pragma unroll
            for (int kt = 0; kt < KT; ++kt) {
                s16x8 a = *(const s16x8*)(ap + kt * 64);
                acc0 = __builtin_amdgcn_mfma_f32_16x16x32_bf16(a, bfr0[kt], acc0, 0, 0, 0);
                acc1 = __builtin_amdgcn_mfma_f32_16x16x32_bf16(a, bfr1[kt], acc1, 0, 0, 0);
            }

            // ---- nonlinearity via shfl_xor(8,16); no LDS round trip ----
            const bool hi = (lm & 8) != 0;
            float hv[4];
#pragma unroll
            for (int r = 0; r < 4; ++r) {
                float a0 = acc0[r] + bv0;
                float a1 = acc1[r] + bv1;
                float a0x = __shfl_xor(a0, 8, 16);
                float a1x = __shfl_xor(a1, 8, 16);
                float iv = hi ? a0x : a0;
                float fv = hi ? a0  : a0x;
                float gv = hi ? a1x : a1;
                float ov = hi ? a1  : a1x;
                float cn = sigm(fv) * cst[r] + sigm(iv) * tanhc(gv);
                cst[r] = cn;
                hv[r] = sigm(ov) * tanhc(cn);
            }

            // ---- 8x4 register transpose -> packed 8-B h stores ----
            // Lane lm(<8) of quad lq ends with row lq*4+(lm>>1),
            // cols w*8+(lm&1)*4..+3.
            ull packed = 0;
#pragma unroll
            for (int r = 0; r < 4; ++r)
                packed |= ((ull)f2bf(hv[r])) << (16 * r);
            ull outp = 0;
            const int rp = (lm >> 1) & 3;
#pragma unroll
            for (int e = 0; e < 4; ++e) {
                ull got = __shfl(packed, (lm & 1) * 4 + e, 16);
                ull val = (got >> (16 * rp)) & 0xFFFFull;
                outp |= val << (16 * e);
            }
            if (lm < 8) {
                int brow = lq * 4 + (lm >> 1);
                size_t off = (size_t)(pw * 128 + g * 16 + brow) * 512
                           + rt * 32 + w * 8 + (lm & 1) * 4;
                __hip_atomic_store((ull*)(hself + off), outp,
                                   __ATOMIC_RELAXED, __HIP_MEMORY_SCOPE_SYSTEM);
            }
        }

        // ---- publish: syncthreads drains vmcnt(0) per wave, then tag ----
        __syncthreads();
        if (tid == 0)
            __hip_atomic_store(mytag, (unsigned)(s + 1),
                               __ATOMIC_RELAXED, __HIP_MEMORY_SCOPE_SYSTEM);
    }
}

__launch_bounds__(256, 1)
__global__ void k_lstm(const float* __restrict__ x,
                       const float* __restrict__ b0,
                       const float* __restrict__ b1,
                       const unsigned short* __restrict__ wsB0,
                       const unsigned short* __restrict__ wsB1,
                       unsigned short* hb0, unsigned short* hb1,
                       unsigned* tags) {
    __shared__ __align__(16) char Atile[16 * 2112];      // A tile, max pitch (L1)

    const int tid = threadIdx.x;
    const int g = blockIdx.x & 7, sub = blockIdx.x >> 3;
    const int layer = sub >> 4, rt = sub & 15;
    const int w = tid >> 6, lane = tid & 63;
    const int lm = lane & 15;

    unsigned* gtags = tags + (size_t)g * 32 * 32;        // 32 tags, 128-B spaced
    unsigned* mytag = gtags + (size_t)(layer * 16 + rt) * 32;

    const float* bias = layer ? b1 : b0;
    const int jsub = rt * 32 + w * 8 + (lm & 7);
    const int G0 = (lm & 8) ? 1 : 0;                     // acc0: i | f
    const float bv0 = bias[G0 * 512 + jsub];
    const float bv1 = bias[(G0 + 2) * 512 + jsub];       // acc1: g | o

    if (layer == 0)
        run_layer<0, 24>(x, wsB0, hb0, hb0, gtags, mytag, bv0, bv1,
                         g, rt, w, lane, tid, Atile);
    else
        run_layer<1, 32>(x, wsB1, hb0, hb1, gtags, mytag, bv0, bv1,
                         g, rt, w, lane, tid, Atile);
}

// ---------------------------------------------------------------------------
// FC epilogue: out[i] = dot(hn[i], fc_w) + fc_b, hn = [h0(511); h1(511)]
// h0(511) was written at epoch 511 -> slot 1; h1(511) at epoch 512 -> slot 0.
// ---------------------------------------------------------------------------
__global__ void k_fc(const unsigned short* __restrict__ hb0,
                     const unsigned short* __restrict__ hb1,
                     const float* __restrict__ fcw, const float* __restrict__ fcb,
                     float* __restrict__ out) {
    int i = blockIdx.x, lane = threadIdx.x;
    const unsigned short* hrow = (i < 128) ? (hb0 + (size_t)(128 + i) * 512)      // slot 1
                                           : (hb1 + (size_t)(i - 128) * 512);     // slot 0
    float ssum = 0.f;
    int j0 = lane * 8;
#pragma unroll
    for (int e = 0; e < 8; ++e) ssum += bf2f(hrow[j0 + e]) * fcw[j0 + e];
#pragma unroll
    for (int off2 = 32; off2 > 0; off2 >>= 1) ssum += __shfl_down(ssum, off2);
    if (lane == 0) out[i] = ssum + fcb[0];
}

// ---------------------------------------------------------------------------
extern "C" void kernel_launch(void* const* d_in, const int* in_sizes, int n_in,
                              void* d_out, int out_size, void* d_ws, size_t ws_size,
                              hipStream_t stream) {
    const float* x    = (const float*)d_in[0];
    const float* wih0 = (const float*)d_in[1];
    const float* whh0 = (const float*)d_in[2];
    const float* b0   = (const float*)d_in[3];
    const float* wih1 = (const float*)d_in[4];
    const float* whh1 = (const float*)d_in[5];
    const float* b1   = (const float*)d_in[6];
    const float* fcw  = (const float*)d_in[7];
    const float* fcb  = (const float*)d_in[8];

    unsigned short* wsB0 = (unsigned short*)d_ws;
    unsigned short* wsB1 = wsB0 + WSB1_OFF;
    unsigned short* hb0  = wsB0 + HB0_OFF;
    unsigned short* hb1  = wsB0 + HB1_OFF;
    unsigned* tags = (unsigned*)((char*)d_ws + TAGS_BYTE_OFF);
    float* out = (float*)d_out;

    k_prep<<<dim3(1857), dim3(256), 0, stream>>>(wih0, whh0, wih1, whh1,
                                                 wsB0, wsB1, hb0, hb1, tags);

    k_lstm<<<dim3(256), dim3(256), 0, stream>>>(x, b0, b1, wsB0, wsB1, hb0, hb1, tags);

    k_fc<<<dim3(256), dim3(64), 0, stream>>>(hb0, hb1, fcw, fcb, out);
}